// Round 2
// baseline (13874.591 us; speedup 1.0000x reference)
//
#include <hip/hip_runtime.h>
#include <cstdint>
#include <cstddef>

// Problem constants (from reference): V=50000, E=300, NF=1, H=256,
// B=128, TH=32, TB=512, NC=4.
#define H_    256
#define NG    768      // 512 gate cols (r|u) + 256 candidate cols, packed
#define BATCH 128
#define TH_   32
#define TB_   512
#define E_    300

// ---------------------------------------------------------------------------
// Pack weights: Bx[k][j] (input rows of Wg|Wc), Wh[k][j] (recurrent rows),
// bias[j] = [bg | bc]. j<512 -> Wg col j ; j>=512 -> Wc col j-512.
// ---------------------------------------------------------------------------
__global__ __launch_bounds__(256) void pack_k(
    const float* __restrict__ Wg, const float* __restrict__ bg,
    const float* __restrict__ Wc, const float* __restrict__ bc, int din,
    float* __restrict__ Bx, float* __restrict__ Wh, float* __restrict__ bias)
{
  int idx = blockIdx.x * 256 + threadIdx.x;
  if (idx < NG) bias[idx] = (idx < 2 * H_) ? bg[idx] : bc[idx - 2 * H_];
  int tot = (din + H_) * NG;
  if (idx >= tot) return;
  int k = idx / NG, j = idx % NG;
  float v = (j < 2 * H_) ? Wg[k * 2 * H_ + j] : Wc[k * H_ + (j - 2 * H_)];
  if (k < din) Bx[(size_t)k * NG + j] = v;
  else         Wh[(size_t)(k - din) * NG + j] = v;
}

// ---------------------------------------------------------------------------
// seqlen[b] = #nonzero ids in row b (equals reference's sign-of-max a.s.;
// valid steps form a prefix by construction).
// ---------------------------------------------------------------------------
__global__ __launch_bounds__(256) void seq_k(const int* __restrict__ ids, int T,
                                             int* __restrict__ seq)
{
  __shared__ int red[256];
  int b = blockIdx.x, tid = threadIdx.x;
  int cnt = 0;
  for (int t = tid; t < T; t += 256) cnt += (ids[b * T + t] != 0) ? 1 : 0;
  red[tid] = cnt;
  __syncthreads();
  for (int s = 128; s > 0; s >>= 1) {
    if (tid < s) red[tid] += red[tid + s];
    __syncthreads();
  }
  if (tid == 0) seq[b] = red[0];
}

// ---------------------------------------------------------------------------
// Input-projection GEMM over a time-chunk:
//   G[row, 0:768] = A[row, :K] @ Bp[K, 768] + bias,  row = b*tc + tlocal.
// A source: either chunk-local dense rows (Adir, stride K) or gathered
// embedding rows emb[ids[(row/tc)*T + t0 + row%tc]].
// 64x64 tile, Ktile 16, 4x4 per thread, fp32.
// ---------------------------------------------------------------------------
__global__ __launch_bounds__(256) void gemm_in(
    const float* __restrict__ Adir, const int* __restrict__ ids,
    const float* __restrict__ emb,
    const float* __restrict__ Bp, const float* __restrict__ bias,
    float* __restrict__ G, int nrows, int K, int t0, int tc, int T)
{
  __shared__ float As[16][68];
  __shared__ float Bs[16][64];
  const int tid = threadIdx.x;
  const int m0 = blockIdx.x * 64;
  const int n0 = blockIdx.y * 64;
  const int tm = (tid >> 4) * 4;
  const int tn = (tid & 15) * 4;
  const int la_r = tid >> 4;    // row within 64-row tile (per pass)
  const int la_k = tid & 15;    // k within tile
  const int lb_n = tid & 63;
  const int lb_k = tid >> 6;    // 0..3
  float acc[4][4] = {{0.f}};

  for (int k0 = 0; k0 < K; k0 += 16) {
#pragma unroll
    for (int p = 0; p < 4; ++p) {
      int r = p * 16 + la_r;
      int row = m0 + r;
      int kg = k0 + la_k;
      float v = 0.f;
      if (row < nrows && kg < K) {
        if (Adir) {
          v = Adir[(size_t)row * K + kg];
        } else {
          int b = row / tc, tl = row % tc;
          v = emb[(size_t)ids[b * T + t0 + tl] * K + kg];
        }
      }
      As[la_k][r] = v;
    }
#pragma unroll
    for (int p = 0; p < 4; ++p) {
      int kl = p * 4 + lb_k;
      int kg = k0 + kl;
      Bs[kl][lb_n] = (kg < K) ? Bp[(size_t)kg * NG + n0 + lb_n] : 0.f;
    }
    __syncthreads();
#pragma unroll
    for (int kk = 0; kk < 16; ++kk) {
      float a0 = As[kk][tm + 0], a1 = As[kk][tm + 1];
      float a2 = As[kk][tm + 2], a3 = As[kk][tm + 3];
      float b0 = Bs[kk][tn + 0], b1 = Bs[kk][tn + 1];
      float b2 = Bs[kk][tn + 2], b3 = Bs[kk][tn + 3];
      acc[0][0] += a0 * b0; acc[0][1] += a0 * b1; acc[0][2] += a0 * b2; acc[0][3] += a0 * b3;
      acc[1][0] += a1 * b0; acc[1][1] += a1 * b1; acc[1][2] += a1 * b2; acc[1][3] += a1 * b3;
      acc[2][0] += a2 * b0; acc[2][1] += a2 * b1; acc[2][2] += a2 * b2; acc[2][3] += a2 * b3;
      acc[3][0] += a3 * b0; acc[3][1] += a3 * b1; acc[3][2] += a3 * b2; acc[3][3] += a3 * b3;
    }
    __syncthreads();
  }
#pragma unroll
  for (int i = 0; i < 4; ++i) {
    int row = m0 + tm + i;
    if (row < nrows) {
#pragma unroll
      for (int j = 0; j < 4; ++j)
        G[(size_t)row * NG + n0 + tn + j] = acc[i][j] + bias[n0 + tn + j];
    }
  }
}

// ---------------------------------------------------------------------------
// GRU recurrence over one time-chunk. One block = one batch row, 512 threads.
// state[b,:] carries h between chunk launches (init to 0 when t0==0).
// Per step: phase A: tid computes gate col tid (0..511); r*h and u exchanged
// via LDS; phase B: tid<256 computes candidate col tid, updates h.
// Weights streamed from L2 (786 KB/layer fits per-XCD L2). 2 barriers/step.
// ---------------------------------------------------------------------------
__global__ __launch_bounds__(512) void gru_chunk(
    const float* __restrict__ G, const float* __restrict__ Wh,
    const int* __restrict__ seq, float* __restrict__ outp,
    float* __restrict__ state, int t0, int tc)
{
  const int b = blockIdx.x;
  const int tid = threadIdx.x;
  __shared__ float h[H_], rh[H_], us[H_];
  if (tid < H_) h[tid] = (t0 == 0) ? 0.f : state[(size_t)b * H_ + tid];
  __syncthreads();
  int steps = seq[b] - t0;
  if (steps < 0) steps = 0;
  if (steps > tc) steps = tc;
  for (int tl = 0; tl < steps; ++tl) {
    const float* g = G + ((size_t)b * tc + tl) * NG;
    // Phase A: 512 gate columns (r | u)
    float acc = g[tid];
    const float* w = Wh + tid;
#pragma unroll 8
    for (int k = 0; k < H_; ++k) acc += h[k] * w[(size_t)k * NG];
    float gate = 1.f / (1.f + expf(-acc));
    if (tid < H_) rh[tid] = gate * h[tid];   // r * h
    else          us[tid - H_] = gate;       // u
    __syncthreads();
    // Phase B: 256 candidate columns + state update
    if (tid < H_) {
      float c = g[2 * H_ + tid];
      const float* wc = Wh + 2 * H_ + tid;
#pragma unroll 8
      for (int k = 0; k < H_; ++k) c += rh[k] * wc[(size_t)k * NG];
      c = tanhf(c);
      float u = us[tid];
      float hn = u * h[tid] + (1.f - u) * c;
      h[tid] = hn;                           // only thread tid reads h[tid] here
      if (outp) outp[((size_t)b * tc + tl) * H_ + tid] = hn;
    }
    __syncthreads();   // h visible before next step's phase A
  }
  if (tid < H_) state[(size_t)b * H_ + tid] = h[tid];
}

// ---------------------------------------------------------------------------
// Final prediction: out[b, c] = [h_head | h_body] @ W_pred + b_pred.
// ---------------------------------------------------------------------------
__global__ __launch_bounds__(512) void pred_k(
    const float* __restrict__ hh, const float* __restrict__ hb,
    const float* __restrict__ Wp, const float* __restrict__ bpred,
    float* __restrict__ out)
{
  int tid = threadIdx.x;           // 512 = 128 b * 4 c
  int b = tid >> 2, c = tid & 3;
  float acc = bpred[c];
  for (int k = 0; k < H_; ++k) acc += hh[b * H_ + k] * Wp[k * 4 + c];
  for (int k = 0; k < H_; ++k) acc += hb[b * H_ + k] * Wp[(H_ + k) * 4 + c];
  out[b * 4 + c] = acc;
}

// ---------------------------------------------------------------------------
extern "C" void kernel_launch(void* const* d_in, const int* in_sizes, int n_in,
                              void* d_out, int out_size, void* d_ws, size_t ws_size,
                              hipStream_t stream)
{
  (void)in_sizes; (void)n_in; (void)out_size;
  const int*   idsH = (const int*)  d_in[0];
  const int*   idsB = (const int*)  d_in[1];
  const float* emb  = (const float*)d_in[2];
  const float* Wp   = (const float*)d_in[3];
  const float* bp   = (const float*)d_in[4];
  const float* W[4][4];   // [hd0,hd1,bd0,bd1][Wg,bg,Wc,bc]
  for (int s = 0; s < 4; ++s)
    for (int q = 0; q < 4; ++q)
      W[s][q] = (const float*)d_in[5 + s * 4 + q];

  // --- choose time-chunk CH to fit ws_size ---------------------------------
  // fixed floats: packed weights (~1.65M) + states/seq (~0.14M) + slack
  const size_t fixed_f = 2000000;
  int CH = 128;                                  // cap (≈75 MB total)
  while (CH > 8 && (fixed_f + (size_t)BATCH * CH * (NG + H_)) * 4 > ws_size)
    CH >>= 1;
  const int CHH = (CH < TH_) ? CH : TH_;         // head chunk (T=32)

  // --- workspace carve-up --------------------------------------------------
  float* w = (float*)d_ws;
  size_t off = 0;
  auto alloc = [&](size_t n) {
    float* p = w + off; off += (n + 255) & ~(size_t)255; return p;
  };
  int* seqH = (int*)alloc(BATCH);
  int* seqB = (int*)alloc(BATCH);
  float* Bx[4]; float* Whp[4]; float* bi[4];
  const int din[4] = {E_, H_, E_, H_};
  for (int s = 0; s < 4; ++s) {
    Bx[s]  = alloc((size_t)din[s] * NG);
    Whp[s] = alloc((size_t)H_ * NG);
    bi[s]  = alloc(NG);
  }
  float* st0 = alloc((size_t)BATCH * H_);        // layer-0 carry (shared seq.)
  float* hfH = alloc((size_t)BATCH * H_);        // head layer-1 final state
  float* hfB = alloc((size_t)BATCH * H_);        // body layer-1 final state
  float* Gc  = alloc((size_t)BATCH * CH * NG);   // chunk G (layer0; reused l1)
  float* Oc  = alloc((size_t)BATCH * CH * H_);   // chunk layer-0 outputs
  (void)ws_size;

  // 1. pack weights (4 stream-layers)
  for (int s = 0; s < 4; ++s) {
    int tot = (din[s] + H_) * NG;
    pack_k<<<(tot + 255) / 256, 256, 0, stream>>>(
        W[s][0], W[s][1], W[s][2], W[s][3], din[s], Bx[s], Whp[s], bi[s]);
  }
  // 2. seqlens
  seq_k<<<BATCH, 256, 0, stream>>>(idsH, TH_, seqH);
  seq_k<<<BATCH, 256, 0, stream>>>(idsB, TB_, seqB);

  // 3. per-stream chunked pipeline:
  //    gemm0(chunk) -> gru0(chunk) -> gemm1(chunk) -> gru1(chunk)
  auto stream_run = [&](const int* ids, int T, int chs, const int* seq,
                        int l0, int l1, float* hf) {
    int rows = BATCH * chs;
    dim3 g(rows / 64, NG / 64);
    for (int t0 = 0; t0 < T; t0 += chs) {
      gemm_in<<<g, 256, 0, stream>>>(nullptr, ids, emb, Bx[l0], bi[l0], Gc,
                                     rows, E_, t0, chs, T);
      gru_chunk<<<BATCH, 512, 0, stream>>>(Gc, Whp[l0], seq, Oc, st0, t0, chs);
      gemm_in<<<g, 256, 0, stream>>>(Oc, nullptr, nullptr, Bx[l1], bi[l1], Gc,
                                     rows, H_, 0, chs, T);
      gru_chunk<<<BATCH, 512, 0, stream>>>(Gc, Whp[l1], seq, nullptr, hf, t0, chs);
    }
  };
  stream_run(idsH, TH_, CHH, seqH, 0, 1, hfH);   // headline (hd0, hd1)
  stream_run(idsB, TB_, CH,  seqB, 2, 3, hfB);   // body     (bd0, bd1)

  // 4. prediction head
  pred_k<<<1, 512, 0, stream>>>(hfH, hfB, Wp, bp, (float*)d_out);
}